// Round 6
// baseline (417.136 us; speedup 1.0000x reference)
//
#include <hip/hip_runtime.h>

typedef unsigned short u16;
typedef unsigned int u32;
typedef __attribute__((ext_vector_type(8))) short bf16x8;
typedef __attribute__((ext_vector_type(4))) float f32x4;
typedef __attribute__((ext_vector_type(16))) float f32x16;

#define DM 2048
#define SQ_SCALE (0.125f * 1.44269504089f)

__device__ __forceinline__ u16 f2bf(float f) {
  union { float f; u32 u; } v; v.f = f;
  u32 r = v.u + 0x7fffu + ((v.u >> 16) & 1u);
  return (u16)(r >> 16);
}
// pack two floats to (bf16(hi)<<16)|bf16(lo), round-half-up
__device__ __forceinline__ u32 pkrn(float lo, float hi) {
  union { float f; u32 u; } a, b; a.f = lo; b.f = hi;
  return ((a.u + 0x8000u) >> 16) | ((b.u + 0x8000u) & 0xffff0000u);
}
// truncating pack via v_perm: D = {hi[31:16], lo[31:16]} — 1 VALU op
__device__ __forceinline__ u32 pktr(float lo, float hi) {
  union { float f; u32 u; } a, b; a.f = lo; b.f = hi;
  return __builtin_amdgcn_perm(b.u, a.u, 0x07060302u);
}
__device__ __forceinline__ void gload16(const u16* g, u16* l) {
  __builtin_amdgcn_global_load_lds((const __attribute__((address_space(1))) void*)g,
                                   (__attribute__((address_space(3))) void*)l, 16, 0, 0);
}

// fp32 -> bf16 elementwise, 8 elems/thread; z selects tensor (validated r4)
__global__ __launch_bounds__(256) void cast3(const float* __restrict__ a0,
                                             const float* __restrict__ a1,
                                             const float* __restrict__ a2,
                                             u16* __restrict__ o0,
                                             u16* __restrict__ o1,
                                             u16* __restrict__ o2) {
  const float* in; u16* out;
  if (blockIdx.z == 0) { in = a0; out = o0; }
  else if (blockIdx.z == 1) { in = a1; out = o1; }
  else { in = a2; out = o2; }
  size_t i = ((size_t)blockIdx.x * 256 + threadIdx.x) * 8;
  float4 f0 = *(const float4*)(in + i);
  float4 f1 = *(const float4*)(in + i + 4);
  uint4 w = {pkrn(f0.x, f0.y), pkrn(f0.z, f0.w), pkrn(f1.x, f1.y), pkrn(f1.z, f1.w)};
  *(uint4*)(out + i) = w;
}

// fp32 [K][N] -> bf16 [N][K], 64x64 tiles (validated r2-r4)
__global__ __launch_bounds__(256) void transpose_cast(const float* __restrict__ in,
                                                      u16* __restrict__ out,
                                                      int K, int N) {
  __shared__ u16 s[64][72];
  int n0 = blockIdx.x * 64, k0 = blockIdx.y * 64;
  int t = threadIdx.x;
  int r = t >> 2;
  int cc = (t & 3) * 16;
  const float* ip = in + (size_t)(k0 + r) * N + n0 + cc;
  u16 tmp[16];
#pragma unroll
  for (int i = 0; i < 16; i += 4) {
    float4 v = *(const float4*)(ip + i);
    tmp[i] = f2bf(v.x); tmp[i + 1] = f2bf(v.y);
    tmp[i + 2] = f2bf(v.z); tmp[i + 3] = f2bf(v.w);
  }
  *(uint4*)&s[r][cc] = *(uint4*)tmp;
  *(uint4*)&s[r][cc + 8] = *(uint4*)(tmp + 8);
  __syncthreads();
#pragma unroll
  for (int i = 0; i < 16; i++) tmp[i] = s[cc + i][r];
  u16* op = out + (size_t)(n0 + r) * K + k0 + cc;
  *(uint4*)op = *(uint4*)tmp;
  *(uint4*)(op + 8) = *(uint4*)(tmp + 8);
}

// V^T precompute (validated r3-r4)
__global__ __launch_bounds__(256) void transpose_v(const u16* __restrict__ kvb,
                                                   u16* __restrict__ vtb) {
  __shared__ u16 s[64][72];
  int bg = blockIdx.y;
  int t0 = blockIdx.x * 64;
  int t = threadIdx.x;
  int r = t >> 2;
  int cc = (t & 3) * 16;
  const u16* ip = kvb + ((size_t)(bg >> 3) * 2048 + t0 + r) * 1024 + 512 + (bg & 7) * 64 + cc;
  *(uint4*)&s[r][cc] = *(const uint4*)ip;
  *(uint4*)&s[r][cc + 8] = *(const uint4*)(ip + 8);
  __syncthreads();
  u16 tmp[16];
#pragma unroll
  for (int i = 0; i < 16; i++) tmp[i] = s[cc + i][r];
  u16* op = vtb + (size_t)bg * 64 * 2048 + (size_t)r * 2048 + t0 + cc;
  *(uint4*)op = *(uint4*)tmp;
  *(uint4*)(op + 8) = *(uint4*)(tmp + 8);
}

// Fused QKV projection (validated r4)
__global__ __launch_bounds__(256) void gemm_proj(const u16* __restrict__ qb,
                                                 const u16* __restrict__ kb,
                                                 const u16* __restrict__ vb,
                                                 const u16* __restrict__ Bt,
                                                 const float* __restrict__ bqp,
                                                 const float* __restrict__ bkp,
                                                 const float* __restrict__ bvp,
                                                 u16* __restrict__ qhb,
                                                 u16* __restrict__ kvb) {
  __shared__ u16 As[128 * 32];
  __shared__ u16 Bs[128 * 32];
  int n0 = blockIdx.x * 128, m0 = blockIdx.y * 128;
  const u16* A; const float* bias; u16* C; int cw, bofs; float esc;
  if (n0 < 2048)      { A = qb; bias = bqp; C = qhb; cw = 2048; bofs = 0;    esc = SQ_SCALE; }
  else if (n0 < 2560) { A = kb; bias = bkp; C = kvb; cw = 1024; bofs = 2048; esc = 1.0f; }
  else                { A = vb; bias = bvp; C = kvb; cw = 1024; bofs = 2560; esc = 1.0f; }
  int ccol0 = (n0 < 2048) ? n0 : (n0 - 2048);

  int tid = threadIdx.x, wave = tid >> 6, lane = tid & 63;
  int lq = lane & 15, quad = lane >> 4;
  int wm = (wave & 1) * 64, wn = (wave >> 1) * 64;

  f32x4 zero = {0.f, 0.f, 0.f, 0.f};
  f32x4 acc[4][4];
#pragma unroll
  for (int i = 0; i < 4; i++)
#pragma unroll
    for (int j = 0; j < 4; j++) acc[i][j] = zero;

  const u16* gA = A + (size_t)(m0 + wave * 16 + (lane >> 2)) * 2048 + (lane & 3) * 8;
  const u16* gB = Bt + (size_t)(n0 + wave * 16 + (lane >> 2)) * 2048 + (lane & 3) * 8;
  u16* lA0 = &As[(wave * 16) * 32];
  u16* lA1 = &As[(64 + wave * 16) * 32];
  u16* lB0 = &Bs[(wave * 16) * 32];
  u16* lB1 = &Bs[(64 + wave * 16) * 32];

  for (int k0 = 0; k0 < 2048; k0 += 32) {
    __syncthreads();
    gload16(gA + k0, lA0);
    gload16(gA + (size_t)64 * 2048 + k0, lA1);
    gload16(gB + k0, lB0);
    gload16(gB + (size_t)64 * 2048 + k0, lB1);
    __syncthreads();
    bf16x8 af[4], bf[4];
#pragma unroll
    for (int i = 0; i < 4; i++) af[i] = *(const bf16x8*)&As[(wm + i * 16 + lq) * 32 + quad * 8];
#pragma unroll
    for (int j = 0; j < 4; j++) bf[j] = *(const bf16x8*)&Bs[(wn + j * 16 + lq) * 32 + quad * 8];
#pragma unroll
    for (int i = 0; i < 4; i++)
#pragma unroll
      for (int j = 0; j < 4; j++)
        acc[i][j] = __builtin_amdgcn_mfma_f32_16x16x32_bf16(af[i], bf[j], acc[i][j], 0, 0, 0);
  }
#pragma unroll
  for (int j = 0; j < 4; j++) {
    int nglob = n0 + wn + j * 16 + lq;
    float bv = bias[nglob - bofs];
    int col = ccol0 + wn + j * 16 + lq;
#pragma unroll
    for (int i = 0; i < 4; i++) {
#pragma unroll
      for (int rg = 0; rg < 4; rg++) {
        int row = m0 + wm + i * 16 + quad * 4 + rg;
        C[(size_t)row * cw + col] = f2bf((acc[i][j][rg] + bv) * esc);
      }
    }
  }
}

// O projection: fp32 C out (validated r4)
__global__ __launch_bounds__(256) void gemm_o(const u16* __restrict__ A,
                                              const u16* __restrict__ Bt,
                                              const float* __restrict__ bias,
                                              float* __restrict__ C) {
  __shared__ u16 As[128 * 32];
  __shared__ u16 Bs[128 * 32];
  int n0 = blockIdx.x * 128, m0 = blockIdx.y * 128;
  int tid = threadIdx.x, wave = tid >> 6, lane = tid & 63;
  int lq = lane & 15, quad = lane >> 4;
  int wm = (wave & 1) * 64, wn = (wave >> 1) * 64;

  f32x4 zero = {0.f, 0.f, 0.f, 0.f};
  f32x4 acc[4][4];
#pragma unroll
  for (int i = 0; i < 4; i++)
#pragma unroll
    for (int j = 0; j < 4; j++) acc[i][j] = zero;

  const u16* gA = A + (size_t)(m0 + wave * 16 + (lane >> 2)) * 2048 + (lane & 3) * 8;
  const u16* gB = Bt + (size_t)(n0 + wave * 16 + (lane >> 2)) * 2048 + (lane & 3) * 8;
  u16* lA0 = &As[(wave * 16) * 32];
  u16* lA1 = &As[(64 + wave * 16) * 32];
  u16* lB0 = &Bs[(wave * 16) * 32];
  u16* lB1 = &Bs[(64 + wave * 16) * 32];

  for (int k0 = 0; k0 < 2048; k0 += 32) {
    __syncthreads();
    gload16(gA + k0, lA0);
    gload16(gA + (size_t)64 * 2048 + k0, lA1);
    gload16(gB + k0, lB0);
    gload16(gB + (size_t)64 * 2048 + k0, lB1);
    __syncthreads();
    bf16x8 af[4], bf[4];
#pragma unroll
    for (int i = 0; i < 4; i++) af[i] = *(const bf16x8*)&As[(wm + i * 16 + lq) * 32 + quad * 8];
#pragma unroll
    for (int j = 0; j < 4; j++) bf[j] = *(const bf16x8*)&Bs[(wn + j * 16 + lq) * 32 + quad * 8];
#pragma unroll
    for (int i = 0; i < 4; i++)
#pragma unroll
      for (int j = 0; j < 4; j++)
        acc[i][j] = __builtin_amdgcn_mfma_f32_16x16x32_bf16(af[i], bf[j], acc[i][j], 0, 0, 0);
  }
#pragma unroll
  for (int j = 0; j < 4; j++) {
    int col = n0 + wn + j * 16 + lq;
    float bv = bias[col];
#pragma unroll
    for (int i = 0; i < 4; i++) {
#pragma unroll
      for (int rg = 0; rg < 4; rg++) {
        int row = m0 + wm + i * 16 + quad * 4 + rg;
        C[(size_t)row * 2048 + col] = acc[i][j][rg] + bv;
      }
    }
  }
}

// Flash attention v4: attn2's validated staging/barrier core, retiled to
// 32 s-rows per wave (grid 16x64 = 1024 blocks), pktr pack + ones-MFMA l.
__global__ __launch_bounds__(256) void attn4(const u16* __restrict__ qh,
                                             const u16* __restrict__ kvb,
                                             const u16* __restrict__ vtb,
                                             u16* __restrict__ out) {
  __shared__ u16 Ks[32][72];   // [t][d]
  __shared__ u16 Vs[64][40];   // [d][t]
  int head = blockIdx.y;
  int schunk = blockIdx.x;
  int b = head >> 5, g = (head >> 2) & 7, h = head & 3;
  int tid = threadIdx.x, wave = tid >> 6, lane = tid & 63;
  int lh = lane & 31, hi = lane >> 5;
  const int qoff = (g * 4 + h) * 64;
  const int koff = g * 64;
  int sBase = schunk * 128 + wave * 32;

  // Q as B-operand (S^T = K.Q^T): n=s=lh, k=d=st*16+hi*8+j
  bf16x8 qf[4];
#pragma unroll
  for (int st = 0; st < 4; st++)
    qf[st] = *(const bf16x8*)(qh + (size_t)(b * 2048 + sBase + lh) * DM + qoff + st * 16 + hi * 8);

  f32x16 o0, o1, lac;
#pragma unroll
  for (int r = 0; r < 16; r++) { o0[r] = 0.f; o1[r] = 0.f; lac[r] = 0.f; }

  const bf16x8 ones = {(short)0x3F80, (short)0x3F80, (short)0x3F80, (short)0x3F80,
                       (short)0x3F80, (short)0x3F80, (short)0x3F80, (short)0x3F80};

  int sr = tid >> 3, sc = (tid & 7) * 8;  // K staging: t-row, d-chunk
  int vd = tid >> 2, vc = (tid & 3) * 8;  // V^T staging: d-row, t-chunk
  const u16* kbase = kvb + (size_t)b * 2048 * 1024 + koff;
  const u16* vbase = vtb + (size_t)(head >> 2) * 64 * 2048 + (size_t)vd * 2048;

  uint4 kreg = *(const uint4*)(kbase + (size_t)sr * 1024 + sc);
  uint4 vreg = *(const uint4*)(vbase + vc);

  for (int t0 = 0; t0 < 2048; t0 += 32) {
    __syncthreads();
    *(uint4*)&Ks[sr][sc] = kreg;
    *(uint4*)&Vs[vd][vc] = vreg;
    __syncthreads();
    int tn = (t0 + 32 < 2048) ? t0 + 32 : 0;  // dummy-safe prefetch
    kreg = *(const uint4*)(kbase + (size_t)(tn + sr) * 1024 + sc);
    vreg = *(const uint4*)(vbase + tn + vc);

    bf16x8 kf[4], vf[2][2];
#pragma unroll
    for (int st = 0; st < 4; st++) kf[st] = *(const bf16x8*)&Ks[lh][st * 16 + hi * 8];
#pragma unroll
    for (int T = 0; T < 2; T++)
#pragma unroll
      for (int db = 0; db < 2; db++)
        vf[T][db] = *(const bf16x8*)&Vs[db * 32 + lh][T * 16 + hi * 8];

    f32x16 st_acc;
#pragma unroll
    for (int r = 0; r < 16; r++) st_acc[r] = 0.f;
#pragma unroll
    for (int st = 0; st < 4; st++)
      st_acc = __builtin_amdgcn_mfma_f32_32x32x16_bf16(kf[st], qf[st], st_acc, 0, 0, 0);

    // S^T C-layout: lane holds col s=lh, rows t=(r&3)+8*(r>>2)+4*hi
    float pr[16];
#pragma unroll
    for (int r = 0; r < 16; r++) pr[r] = __builtin_amdgcn_exp2f(st_acc[r]);
    u32 pk[8];
#pragma unroll
    for (int a = 0; a < 4; a++) {
      pk[2 * a] = pktr(pr[4 * a], pr[4 * a + 1]);
      pk[2 * a + 1] = pktr(pr[4 * a + 2], pr[4 * a + 3]);
    }
#pragma unroll
    for (int T = 0; T < 2; T++) {
      u32 E0 = hi ? pk[4 * T] : pk[4 * T + 2];
      u32 E1 = hi ? pk[4 * T + 1] : pk[4 * T + 3];
      u32 X0 = __shfl_xor(E0, 32);
      u32 X1 = __shfl_xor(E1, 32);
      union { u32 u[4]; bf16x8 v; } af;
      af.u[0] = hi ? X0 : pk[4 * T];
      af.u[1] = hi ? X1 : pk[4 * T + 1];
      af.u[2] = hi ? pk[4 * T + 2] : X0;
      af.u[3] = hi ? pk[4 * T + 3] : X1;
      lac = __builtin_amdgcn_mfma_f32_32x32x16_bf16(af.v, ones, lac, 0, 0, 0);
      o0 = __builtin_amdgcn_mfma_f32_32x32x16_bf16(af.v, vf[T][0], o0, 0, 0, 0);
      o1 = __builtin_amdgcn_mfma_f32_32x32x16_bf16(af.v, vf[T][1], o1, 0, 0, 0);
    }
  }

  // epilogue: lac C-layout rows == o C-layout rows (same A, same instruction)
#pragma unroll
  for (int r = 0; r < 16; r++) {
    float inv = 1.0f / lac[r];
    int srow = (r & 3) + 8 * (r >> 2) + 4 * hi;
    size_t base = (size_t)(b * 2048 + sBase + srow) * DM + qoff + lh;
    out[base] = f2bf(o0[r] * inv);
    out[base + 32] = f2bf(o1[r] * inv);
  }
}

extern "C" void kernel_launch(void* const* d_in, const int* in_sizes, int n_in,
                              void* d_out, int out_size, void* d_ws, size_t ws_size,
                              hipStream_t stream) {
  const float* q  = (const float*)d_in[0];
  const float* k  = (const float*)d_in[1];
  const float* v  = (const float*)d_in[2];
  const float* Wq = (const float*)d_in[3];
  const float* bq = (const float*)d_in[4];
  const float* Wk = (const float*)d_in[5];
  const float* bk = (const float*)d_in[6];
  const float* Wv = (const float*)d_in[7];
  const float* bv = (const float*)d_in[8];
  const float* Wo = (const float*)d_in[9];
  const float* bo = (const float*)d_in[10];

  u16* p = (u16*)d_ws;
  u16* WqkvT = p; p += (size_t)3072 * 2048;
  u16* WoT   = p; p += (size_t)2048 * 2048;
  u16* qb    = p; p += (size_t)4096 * 2048;
  u16* kb    = p; p += (size_t)4096 * 2048;
  u16* vb    = p; p += (size_t)4096 * 2048;
  u16* qhb   = p; p += (size_t)4096 * 2048;
  u16* kvb   = p; p += (size_t)4096 * 1024;
  u16* vtb   = p; p += (size_t)16 * 64 * 2048;
  u16* att   = qb;  // reuse: qb dead after gemm_proj

  cast3<<<dim3(4096, 1, 3), 256, 0, stream>>>(q, k, v, qb, kb, vb);

  transpose_cast<<<dim3(32, 32), 256, 0, stream>>>(Wq, WqkvT, 2048, 2048);
  transpose_cast<<<dim3(8, 32), 256, 0, stream>>>(Wk, WqkvT + (size_t)2048 * 2048, 2048, 512);
  transpose_cast<<<dim3(8, 32), 256, 0, stream>>>(Wv, WqkvT + (size_t)2560 * 2048, 2048, 512);
  transpose_cast<<<dim3(32, 32), 256, 0, stream>>>(Wo, WoT, 2048, 2048);

  gemm_proj<<<dim3(24, 32), 256, 0, stream>>>(qb, kb, vb, WqkvT, bq, bk, bv, qhb, kvb);

  transpose_v<<<dim3(32, 16), 256, 0, stream>>>(kvb, vtb);

  attn4<<<dim3(16, 64), 256, 0, stream>>>(qhb, kvb, vtb, att);

  gemm_o<<<dim3(16, 32), 256, 0, stream>>>(att, WoT, bo, (float*)d_out);
}